// Round 10
// baseline (257.203 us; speedup 1.0000x reference)
//
#include <hip/hip_runtime.h>
#include <hip/hip_bf16.h>

typedef __bf16 bf16x8 __attribute__((ext_vector_type(8)));
typedef __bf16 bf16x4 __attribute__((ext_vector_type(4)));
typedef float f32x4 __attribute__((ext_vector_type(4)));

#define NB 4
#define NS 2048
#define ND 1024
#define NH 16
#define NDH 64
#define NM (NB*NS)   // 8192

#define MFMA(a,b,c) __builtin_amdgcn_mfma_f32_16x16x32_bf16((a),(b),(c),0,0,0)

__device__ __forceinline__ void gload16(const void* g, void* l) {
    __builtin_amdgcn_global_load_lds(
        (const __attribute__((address_space(1))) void*)(g),
        (__attribute__((address_space(3))) void*)(l),
        16, 0, 0);
}

// ---------------- cast fp32 -> bf16, vectorized ----------------
__global__ __launch_bounds__(256) void cast4(const float* __restrict__ in,
                                             __bf16* __restrict__ out, int n) {
    int i = (blockIdx.x * 256 + threadIdx.x) * 4;
    if (i >= n) return;
    float4 v = *(const float4*)(in + i);
    bf16x4 o;
    o[0] = (__bf16)v.x; o[1] = (__bf16)v.y; o[2] = (__bf16)v.z; o[3] = (__bf16)v.w;
    *(bf16x4*)(out + i) = o;
}

// ---------------- 128x128 GEMM, A[M,K] * W[N,K]^T ----------------
// MODE 0: z=0 -> Q [B,H,S,Dh] (scaled by 1/8*log2e), z=1 -> K, z=2 -> V^T [B,H,Dh,S]
// MODE 1: C fp32 row-major [M,N]
template<int MODE>
__global__ __launch_bounds__(256) void gemm128(
    const __bf16* __restrict__ A,
    const __bf16* __restrict__ W0, const __bf16* __restrict__ W1,
    const __bf16* __restrict__ W2,
    __bf16* __restrict__ O0, __bf16* __restrict__ O1, __bf16* __restrict__ O2,
    float* __restrict__ Cf)
{
    __shared__ alignas(16) __bf16 As[128*32];
    __shared__ alignas(16) __bf16 Bs[128*32];

    const int tid  = threadIdx.x;
    const int wave = tid >> 6, lane = tid & 63;
    const int l16  = lane & 15, lq = lane >> 4;
    const int bm = blockIdx.x * 128;
    const int bn = blockIdx.y * 128;
    const int z  = (MODE == 0) ? blockIdx.z : 0;
    const __bf16* __restrict__ Bw =
        (MODE == 0) ? ((z == 0) ? W0 : (z == 1) ? W1 : W2) : W0;

    const int wr = (wave >> 1) * 64;
    const int wc = (wave & 1) * 64;

    f32x4 acc[4][4];
    #pragma unroll
    for (int i = 0; i < 4; i++)
        #pragma unroll
        for (int j = 0; j < 4; j++)
            acc[i][j] = (f32x4){0.f, 0.f, 0.f, 0.f};

    const int ch0 = tid, ch1 = tid + 256;
    const int r0 = ch0 >> 2, c0 = (ch0 & 3) * 8;
    const int r1 = ch1 >> 2, c1 = (ch1 & 3) * 8;

    for (int k0 = 0; k0 < ND; k0 += 32) {
        __syncthreads();
        gload16(A  + (size_t)(bm + r0) * ND + k0 + c0, As + ch0 * 8);
        gload16(Bw + (size_t)(bn + r0) * ND + k0 + c0, Bs + ch0 * 8);
        gload16(A  + (size_t)(bm + r1) * ND + k0 + c1, As + ch1 * 8);
        gload16(Bw + (size_t)(bn + r1) * ND + k0 + c1, Bs + ch1 * 8);
        __syncthreads();

        bf16x8 af[4], bf[4];
        #pragma unroll
        for (int i = 0; i < 4; i++) {
            af[i] = *(const bf16x8*)(As + (wr + i*16 + l16) * 32 + lq * 8);
            bf[i] = *(const bf16x8*)(Bs + (wc + i*16 + l16) * 32 + lq * 8);
        }
        #pragma unroll
        for (int i = 0; i < 4; i++)
            #pragma unroll
            for (int j = 0; j < 4; j++)
                acc[i][j] = MFMA(af[i], bf[j], acc[i][j]);
    }

    #pragma unroll
    for (int i = 0; i < 4; i++) {
        #pragma unroll
        for (int j = 0; j < 4; j++) {
            #pragma unroll
            for (int r = 0; r < 4; r++) {
                int row = bm + wr + i*16 + lq*4 + r;   // m index (b*S + s)
                int col = bn + wc + j*16 + l16;        // n index (d_out)
                float v = acc[i][j][r];
                if (MODE == 1) {
                    Cf[(size_t)row * ND + col] = v;
                } else {
                    if (z == 0) v *= 0.1803368801111204f;  // 1/8 * log2(e)
                    int b = row >> 11, s = row & 2047;
                    int h = col >> 6,  dh = col & 63;
                    if (z < 2) {
                        __bf16* dst = (z == 0) ? O0 : O1;
                        dst[(((size_t)b*NH + h)*NS + s)*NDH + dh] = (__bf16)v;
                    } else {
                        O2[(((size_t)b*NH + h)*NDH + dh)*NS + s] = (__bf16)v;
                    }
                }
            }
        }
    }
}

// ------- causal flash attention: swapped-QK^T, per-lane deferred softmax ----
// Task = (bh, 32-row q-block j). LPT block order: bid -> kk = 31-(bid>>5);
// block's 4 waves all have ntk = kk+1 tiles (equal length), long blocks
// dispatch first -> HW backfill balances CUs. wave&1 picks bh within a pair,
// wave>>1 picks j in {2kk, 2kk+1}; waves {0,2} share bh (L1/L2 reuse).
// Steady-state tiles use ZERO cross-lane ops: each lane tracks only its own
// 16 kv-scores vs mr+8 (defer-max); true row-max (2 shfl) + o-rescale only on
// rare trigger. lsum is a per-lane partial, quad-reduced once in epilogue.
// P relayout: 4x ds_write_b64 per qi into stride-72 rows (no pow-2 conflicts).
__global__ __launch_bounds__(256, 2) void attn_sw(
    const __bf16* __restrict__ Q, const __bf16* __restrict__ K,
    const __bf16* __restrict__ Vt, __bf16* __restrict__ Oa)
{
    __shared__ alignas(16) __bf16 Ps[4][32*72];  // per-wave [q][kv], stride 72
    __shared__ float Fs[4][32];                  // per-wave fac/lsum transport

    const int tid  = threadIdx.x;
    const int wave = tid >> 6, lane = tid & 63;
    const int l16  = lane & 15, lq = lane >> 4;

    const int bid = blockIdx.x;                   // 0..1023
    const int kk  = 31 - (bid >> 5);              // 31..0  (LPT: long first)
    const int bh  = ((bid & 31) << 1) | (wave & 1);   // 0..63
    const int j   = kk * 2 + (wave >> 1);         // q-block index
    const int q0  = j * 32;
    const int ntk = kk + 1;                       // kv tiles for this task

    const int b = bh >> 4, h = bh & 15;
    const size_t qkb = (size_t)bh * NS * NDH;     // Q,K  [bh][s][dh]
    const size_t vbb = (size_t)bh * NDH * NS;     // Vt   [bh][dh][s]
    __bf16* Pw = Ps[wave];
    float*  Fw = Fs[wave];

    // Q fragments (B-operand): q = qi*16+l16, k-chunk = lq*8
    bf16x8 qf[2][2];
    #pragma unroll
    for (int qi = 0; qi < 2; qi++) {
        const __bf16* qr = Q + qkb + (size_t)(q0 + qi*16 + l16) * NDH;
        qf[qi][0] = *(const bf16x8*)(qr + lq * 8);
        qf[qi][1] = *(const bf16x8*)(qr + 32 + lq * 8);
    }

    // o[qi][d]: row q = qi*16 + lq*4 + r, col = d*16 + l16
    f32x4 o[2][4];
    #pragma unroll
    for (int qi = 0; qi < 2; qi++)
        #pragma unroll
        for (int d = 0; d < 4; d++)
            o[qi][d] = (f32x4){0.f, 0.f, 0.f, 0.f};
    // softmax state for lane's q = qi*16 + l16; lsum is a PARTIAL over this
    // lane's kv slots only (quad-reduced at the end)
    float mr[2]   = {-__builtin_inff(), -__builtin_inff()};
    float lsum[2] = {0.f, 0.f};

    // running pointers: K A-frag row = l16 (+16 per ni), k-chunk = lq*8
    const __bf16* kpt = K + qkb + (size_t)l16 * NDH + lq * 8;
    const __bf16* vp0 = Vt + vbb + (size_t)l16 * NS + lq * 8;
    const __bf16* vp1 = vp0 + 16 * NS;
    const __bf16* vp2 = vp0 + 32 * NS;
    const __bf16* vp3 = vp0 + 48 * NS;

    #pragma unroll 1
    for (int t = 0; t < ntk; ++t) {
        bf16x8 kf[4][2];
        #pragma unroll
        for (int ni = 0; ni < 4; ni++) {
            kf[ni][0] = *(const bf16x8*)(kpt + ni * 1024);
            kf[ni][1] = *(const bf16x8*)(kpt + ni * 1024 + 32);
        }
        bf16x8 vb[4][2];
        vb[0][0] = *(const bf16x8*)(vp0);      vb[0][1] = *(const bf16x8*)(vp0 + 32);
        vb[1][0] = *(const bf16x8*)(vp1);      vb[1][1] = *(const bf16x8*)(vp1 + 32);
        vb[2][0] = *(const bf16x8*)(vp2);      vb[2][1] = *(const bf16x8*)(vp2 + 32);
        vb[3][0] = *(const bf16x8*)(vp3);      vb[3][1] = *(const bf16x8*)(vp3 + 32);

        const bool diag = (t == ntk - 1);
        const int  dq   = q0 - t * 64;            // 0 (j even) or 32 (j odd) at diag

        #pragma unroll
        for (int qi = 0; qi < 2; qi++) {
            // S[kv][q]: in-lane kv = ni*16 + lq*4 + r, q = l16
            f32x4 s[4];
            __builtin_amdgcn_s_setprio(1);
            #pragma unroll
            for (int ni = 0; ni < 4; ni++) {
                if (diag && ni*16 > dq + qi*16 + 15) {   // fully-masked subtile
                    s[ni] = (f32x4){-__builtin_inff(), -__builtin_inff(),
                                    -__builtin_inff(), -__builtin_inff()};
                } else {
                    f32x4 z = (f32x4){0.f, 0.f, 0.f, 0.f};
                    z = MFMA(kf[ni][0], qf[qi][0], z);
                    z = MFMA(kf[ni][1], qf[qi][1], z);
                    s[ni] = z;
                }
            }
            __builtin_amdgcn_s_setprio(0);

            if (diag) {
                const int qrel = dq + qi*16 + l16;
                #pragma unroll
                for (int ni = 0; ni < 4; ni++)
                    #pragma unroll
                    for (int r = 0; r < 4; r++)
                        if (ni*16 + lq*4 + r > qrel) s[ni][r] = -__builtin_inff();
            }

            // in-lane max of this lane's 16 scores (no cross-lane!)
            float t0 = fmaxf(fmaxf(s[0][0], s[0][1]), fmaxf(s[0][2], s[0][3]));
            float t1 = fmaxf(fmaxf(s[1][0], s[1][1]), fmaxf(s[1][2], s[1][3]));
            float t2 = fmaxf(fmaxf(s[2][0], s[2][1]), fmaxf(s[2][2], s[2][3]));
            float t3 = fmaxf(fmaxf(s[3][0], s[3][1]), fmaxf(s[3][2], s[3][3]));
            float tm = fmaxf(fmaxf(t0, t1), fmaxf(t2, t3));

            // defer-max: rescale only if some lane's local max broke the bound
            if (__any(tm > mr[qi] + 8.f)) {
                float rowm = fmaxf(tm, __shfl_xor(tm, 16));
                rowm = fmaxf(rowm, __shfl_xor(rowm, 32));
                float mnew = fmaxf(mr[qi], rowm);
                float fac  = exp2f(mr[qi] - mnew);
                mr[qi] = mnew;
                lsum[qi] *= fac;
                if (lane < 16) Fw[qi*16 + lane] = fac;
                f32x4 fo = *(const f32x4*)&Fw[qi*16 + lq*4];
                #pragma unroll
                for (int d = 0; d < 4; d++) o[qi][d] *= fo;
            }

            // P = exp2(s - m); per-lane partial sum; 4x b64 writes (r packed)
            __bf16* pr = Pw + (qi*16 + l16) * 72;
            float psum = 0.f;
            #pragma unroll
            for (int ni = 0; ni < 4; ni++) {
                bf16x4 pv4;
                #pragma unroll
                for (int r = 0; r < 4; r++) {
                    float pv = exp2f(s[ni][r] - mr[qi]);
                    psum += pv;
                    pv4[r] = (__bf16)pv;
                }
                *(bf16x4*)(pr + ni*16 + lq*4) = pv4;
            }
            lsum[qi] += psum;

            // PV: A = P row q=l16 (read back from own row), B = V^T rows
            bf16x8 pa0 = *(const bf16x8*)(pr + lq * 8);
            __builtin_amdgcn_s_setprio(1);
            #pragma unroll
            for (int d = 0; d < 4; d++)
                o[qi][d] = MFMA(pa0, vb[d][0], o[qi][d]);
            __builtin_amdgcn_s_setprio(0);
            if (!(diag && dq == 0)) {   // upper kv half all masked on even-j diag
                bf16x8 pa1 = *(const bf16x8*)(pr + 32 + lq * 8);
                __builtin_amdgcn_s_setprio(1);
                #pragma unroll
                for (int d = 0; d < 4; d++)
                    o[qi][d] = MFMA(pa1, vb[d][1], o[qi][d]);
                __builtin_amdgcn_s_setprio(0);
            }
        }

        kpt += 64 * NDH;   // next 64 kv rows
        vp0 += 64; vp1 += 64; vp2 += 64; vp3 += 64;
    }

    // quad-reduce the per-lane lsum partials (once), transport to o-layout
    #pragma unroll
    for (int qi = 0; qi < 2; qi++) {
        float tl = lsum[qi];
        tl += __shfl_xor(tl, 16);
        tl += __shfl_xor(tl, 32);
        lsum[qi] = tl;
    }
    if (lane < 16) { Fw[lane] = lsum[0]; Fw[16 + lane] = lsum[1]; }
    #pragma unroll
    for (int qi = 0; qi < 2; qi++) {
        f32x4 lv = *(const f32x4*)&Fw[qi*16 + lq*4];
        #pragma unroll
        for (int r = 0; r < 4; r++) {
            float inv = 1.f / lv[r];
            int srow = q0 + qi*16 + lq*4 + r;
            #pragma unroll
            for (int d = 0; d < 4; d++)
                Oa[((size_t)b * NS + srow) * ND + h*64 + d*16 + l16] =
                    (__bf16)(o[qi][d][r] * inv);
        }
    }
}

extern "C" void kernel_launch(void* const* d_in, const int* in_sizes, int n_in,
                              void* d_out, int out_size, void* d_ws, size_t ws_size,
                              hipStream_t stream) {
    const float* x  = (const float*)d_in[0];
    const float* wq = (const float*)d_in[1];
    const float* wk = (const float*)d_in[2];
    const float* wv = (const float*)d_in[3];
    const float* wo = (const float*)d_in[4];
    char* ws = (char*)d_ws;

    __bf16* xb  = (__bf16*)(ws);                      // 16 MB  [M,K]
    __bf16* wqb = (__bf16*)(ws + (16ull << 20));      //  2 MB
    __bf16* wkb = (__bf16*)(ws + (18ull << 20));
    __bf16* wvb = (__bf16*)(ws + (20ull << 20));
    __bf16* wob = (__bf16*)(ws + (22ull << 20));
    __bf16* Qb  = (__bf16*)(ws + (24ull << 20));      // 16 MB [B,H,S,Dh]
    __bf16* Kb  = (__bf16*)(ws + (40ull << 20));      // 16 MB [B,H,S,Dh]
    __bf16* Vtb = (__bf16*)(ws + (56ull << 20));      // 16 MB [B,H,Dh,S]
    __bf16* Ab  = (__bf16*)(ws + (72ull << 20));      // 16 MB [B,S,D]
    float* out  = (float*)d_out;

    cast4<<<dim3(NM * ND / 1024), 256, 0, stream>>>(x,  xb,  NM * ND);
    cast4<<<dim3(ND * ND / 1024), 256, 0, stream>>>(wq, wqb, ND * ND);
    cast4<<<dim3(ND * ND / 1024), 256, 0, stream>>>(wk, wkb, ND * ND);
    cast4<<<dim3(ND * ND / 1024), 256, 0, stream>>>(wv, wvb, ND * ND);
    cast4<<<dim3(ND * ND / 1024), 256, 0, stream>>>(wo, wob, ND * ND);

    gemm128<0><<<dim3(NM/128, ND/128, 3), 256, 0, stream>>>(
        xb, wqb, wkb, wvb, Qb, Kb, Vtb, nullptr);

    attn_sw<<<dim3(1024), 256, 0, stream>>>(Qb, Kb, Vtb, Ab);

    gemm128<1><<<dim3(NM/128, ND/128), 256, 0, stream>>>(
        Ab, wob, nullptr, nullptr, nullptr, nullptr, nullptr, out);
}

// Round 11
// 246.974 us; speedup vs baseline: 1.0414x; 1.0414x over previous
//
#include <hip/hip_runtime.h>
#include <hip/hip_bf16.h>

typedef __bf16 bf16x8 __attribute__((ext_vector_type(8)));
typedef __bf16 bf16x4 __attribute__((ext_vector_type(4)));
typedef float f32x4 __attribute__((ext_vector_type(4)));
typedef float f32x16 __attribute__((ext_vector_type(16)));

#define NB 4
#define NS 2048
#define ND 1024
#define NH 16
#define NDH 64
#define NM (NB*NS)   // 8192

#define MFMA(a,b,c)   __builtin_amdgcn_mfma_f32_16x16x32_bf16((a),(b),(c),0,0,0)
#define MFMA32(a,b,c) __builtin_amdgcn_mfma_f32_32x32x16_bf16((a),(b),(c),0,0,0)

__device__ __forceinline__ void gload16(const void* g, void* l) {
    __builtin_amdgcn_global_load_lds(
        (const __attribute__((address_space(1))) void*)(g),
        (__attribute__((address_space(3))) void*)(l),
        16, 0, 0);
}

__device__ __forceinline__ unsigned cvt_pk_bf16(float lo, float hi) {
    unsigned w;
    asm("v_cvt_pk_bf16_f32 %0, %1, %2" : "=v"(w) : "v"(lo), "v"(hi));
    return w;
}
// swap a's upper 32 lanes with b's lower 32 lanes (in place)
#define PLSWAP(a, b) asm("v_permlane32_swap_b32 %0, %1" : "+v"(a), "+v"(b))

// ---------------- cast fp32 -> bf16, vectorized ----------------
__global__ __launch_bounds__(256) void cast4(const float* __restrict__ in,
                                             __bf16* __restrict__ out, int n) {
    int i = (blockIdx.x * 256 + threadIdx.x) * 4;
    if (i >= n) return;
    float4 v = *(const float4*)(in + i);
    bf16x4 o;
    o[0] = (__bf16)v.x; o[1] = (__bf16)v.y; o[2] = (__bf16)v.z; o[3] = (__bf16)v.w;
    *(bf16x4*)(out + i) = o;
}

// ---------------- 128x128 GEMM, A[M,K] * W[N,K]^T ----------------
// MODE 0: z=0 -> Q [B,H,S,Dh] (scaled by 1/8*log2e), z=1 -> K, z=2 -> V^T [B,H,Dh,S]
// MODE 1: C fp32 row-major [M,N]
template<int MODE>
__global__ __launch_bounds__(256) void gemm128(
    const __bf16* __restrict__ A,
    const __bf16* __restrict__ W0, const __bf16* __restrict__ W1,
    const __bf16* __restrict__ W2,
    __bf16* __restrict__ O0, __bf16* __restrict__ O1, __bf16* __restrict__ O2,
    float* __restrict__ Cf)
{
    __shared__ alignas(16) __bf16 As[128*32];
    __shared__ alignas(16) __bf16 Bs[128*32];

    const int tid  = threadIdx.x;
    const int wave = tid >> 6, lane = tid & 63;
    const int l16  = lane & 15, lq = lane >> 4;
    const int bm = blockIdx.x * 128;
    const int bn = blockIdx.y * 128;
    const int z  = (MODE == 0) ? blockIdx.z : 0;
    const __bf16* __restrict__ Bw =
        (MODE == 0) ? ((z == 0) ? W0 : (z == 1) ? W1 : W2) : W0;

    const int wr = (wave >> 1) * 64;
    const int wc = (wave & 1) * 64;

    f32x4 acc[4][4];
    #pragma unroll
    for (int i = 0; i < 4; i++)
        #pragma unroll
        for (int j = 0; j < 4; j++)
            acc[i][j] = (f32x4){0.f, 0.f, 0.f, 0.f};

    const int ch0 = tid, ch1 = tid + 256;
    const int r0 = ch0 >> 2, c0 = (ch0 & 3) * 8;
    const int r1 = ch1 >> 2, c1 = (ch1 & 3) * 8;

    for (int k0 = 0; k0 < ND; k0 += 32) {
        __syncthreads();
        gload16(A  + (size_t)(bm + r0) * ND + k0 + c0, As + ch0 * 8);
        gload16(Bw + (size_t)(bn + r0) * ND + k0 + c0, Bs + ch0 * 8);
        gload16(A  + (size_t)(bm + r1) * ND + k0 + c1, As + ch1 * 8);
        gload16(Bw + (size_t)(bn + r1) * ND + k0 + c1, Bs + ch1 * 8);
        __syncthreads();

        bf16x8 af[4], bf[4];
        #pragma unroll
        for (int i = 0; i < 4; i++) {
            af[i] = *(const bf16x8*)(As + (wr + i*16 + l16) * 32 + lq * 8);
            bf[i] = *(const bf16x8*)(Bs + (wc + i*16 + l16) * 32 + lq * 8);
        }
        #pragma unroll
        for (int i = 0; i < 4; i++)
            #pragma unroll
            for (int j = 0; j < 4; j++)
                acc[i][j] = MFMA(af[i], bf[j], acc[i][j]);
    }

    #pragma unroll
    for (int i = 0; i < 4; i++) {
        #pragma unroll
        for (int j = 0; j < 4; j++) {
            #pragma unroll
            for (int r = 0; r < 4; r++) {
                int row = bm + wr + i*16 + lq*4 + r;   // m index (b*S + s)
                int col = bn + wc + j*16 + l16;        // n index (d_out)
                float v = acc[i][j][r];
                if (MODE == 1) {
                    Cf[(size_t)row * ND + col] = v;
                } else {
                    if (z == 0) v *= 0.1803368801111204f;  // 1/8 * log2(e)
                    int b = row >> 11, s = row & 2047;
                    int h = col >> 6,  dh = col & 63;
                    if (z < 2) {
                        __bf16* dst = (z == 0) ? O0 : O1;
                        dst[(((size_t)b*NH + h)*NS + s)*NDH + dh] = (__bf16)v;
                    } else {
                        O2[(((size_t)b*NH + h)*NDH + dh)*NS + s] = (__bf16)v;
                    }
                }
            }
        }
    }
}

// ------- causal flash attention: 32x32 swapped-QK^T, in-register softmax -----
// Wave-task pair {63-p, p}: every wave does exactly 65 kv-tiles (KVBLK=32) --
// perfectly balanced. 512 blocks x 4 waves; block's 4 waves = 4 consecutive
// heads; head-groups pinned per-XCD via bid&15.
// S = mfma32(K, Q): lane owns q = lane&31; its 16 scores sit at kv =
// crow(r) = (r&3) + 8*(r>>2) + 4*(lane>>5). Softmax fully in-register
// (defer-max, log2 domain, scale pre-folded into Q). P -> PV A-fragment via
// 8x v_cvt_pk_bf16_f32 + 4x v_permlane32_swap_b32 (T12) -- NO LDS round-trip.
// Only LDS: 32 floats/wave to transport rescale/1-over-l across the C-layout.
__global__ __launch_bounds__(256, 2) void attn32(
    const __bf16* __restrict__ Q, const __bf16* __restrict__ K,
    const __bf16* __restrict__ Vt, __bf16* __restrict__ Oa)
{
    __shared__ float Fs[4][32];

    const int tid  = threadIdx.x;
    const int wave = tid >> 6, lane = tid & 63;
    const int qq   = lane & 31, hi = lane >> 5;

    const int bid = blockIdx.x;              // 0..511
    const int p   = bid >> 4;                // 0..31
    const int bh  = (bid & 15) * 4 + wave;   // 0..63
    const int b = bh >> 4, h = bh & 15;
    const size_t qkb = (size_t)bh * NS * NDH;   // Q,K  [bh][s][dh]
    const size_t vbb = (size_t)bh * NDH * NS;   // Vt   [bh][dh][s]
    float* Fw = Fs[wave];

    #pragma unroll 1
    for (int pass = 0; pass < 2; ++pass) {
        const int j   = pass ? p : 63 - p;   // 32-row q-block index
        const int q0  = j * 32;
        const int ntk = j + 1;               // 32-wide kv tiles

        // Q fragments (B-operand): col = q = qq, k = c*16 + hi*8 + (0..7)
        bf16x8 qf[4];
        const __bf16* qr = Q + qkb + (size_t)(q0 + qq) * NDH + hi * 8;
        #pragma unroll
        for (int c = 0; c < 4; c++) qf[c] = *(const bf16x8*)(qr + c * 16);

        f32x16 o0 = (f32x16)0.f, o1 = (f32x16)0.f;  // row=q=crow(r), col=d=qq(+32)
        float mr = -__builtin_inff(), lsum = 0.f;

        // running pointers: K A-frag row = kv = qq, k = hi*8; V B-frag d=qq(+32)
        const __bf16* kpt = K + qkb + (size_t)qq * NDH + hi * 8;
        const __bf16* vt0 = Vt + vbb + (size_t)qq * NS + hi * 8;
        const __bf16* vt1 = vt0 + 32 * NS;

        #pragma unroll 1
        for (int t = 0; t < ntk; ++t) {
            bf16x8 kf[4];
            #pragma unroll
            for (int c = 0; c < 4; c++) kf[c] = *(const bf16x8*)(kpt + c * 16);
            bf16x8 v00 = *(const bf16x8*)(vt0);        // kv 0..15,  d=qq
            bf16x8 v10 = *(const bf16x8*)(vt0 + 16);   // kv 16..31, d=qq
            bf16x8 v01 = *(const bf16x8*)(vt1);        // kv 0..15,  d=qq+32
            bf16x8 v11 = *(const bf16x8*)(vt1 + 16);   // kv 16..31, d=qq+32

            // S[kv][q] = sum_dh K*Q  (scores in log2 units)
            f32x16 s = (f32x16)0.f;
            __builtin_amdgcn_s_setprio(1);
            #pragma unroll
            for (int c = 0; c < 4; c++) s = MFMA32(kf[c], qf[c], s);
            __builtin_amdgcn_s_setprio(0);

            if (t == ntk - 1) {   // diagonal tile: kv0 == q0
                #pragma unroll
                for (int r = 0; r < 16; r++) {
                    const int crow = (r & 3) + 8 * (r >> 2) + 4 * hi;
                    if (crow > qq) s[r] = -__builtin_inff();
                }
            }

            // local max over this lane's 16 scores
            float tm = s[0];
            #pragma unroll
            for (int r = 1; r < 16; r++) tm = fmaxf(tm, s[r]);

            // defer-max: rare rescale; fac transported q(lane) -> q(crow) via LDS
            if (__any(tm > mr + 8.f)) {
                float rowm = fmaxf(tm, __shfl_xor(tm, 32));
                float mnew = fmaxf(mr, rowm);
                float fac  = exp2f(mr - mnew);
                mr = mnew; lsum *= fac;
                if (lane < 32) Fw[qq] = fac;
                f32x4 f0 = *(const f32x4*)&Fw[4 * hi];
                f32x4 f1 = *(const f32x4*)&Fw[8 + 4 * hi];
                f32x4 f2 = *(const f32x4*)&Fw[16 + 4 * hi];
                f32x4 f3 = *(const f32x4*)&Fw[24 + 4 * hi];
                #pragma unroll
                for (int i = 0; i < 4; i++) {
                    o0[i]      *= f0[i]; o1[i]      *= f0[i];
                    o0[4 + i]  *= f1[i]; o1[4 + i]  *= f1[i];
                    o0[8 + i]  *= f2[i]; o1[8 + i]  *= f2[i];
                    o0[12 + i] *= f3[i]; o1[12 + i] *= f3[i];
                }
            }

            // P = exp2(s - m); per-lane partial sum (merged once at the end)
            float pv[16]; float psum = 0.f;
            #pragma unroll
            for (int r = 0; r < 16; r++) { pv[r] = exp2f(s[r] - mr); psum += pv[r]; }
            lsum += psum;

            // pack to bf16 pairs; permlane-swap into PV A-fragment layout
            unsigned w0 = cvt_pk_bf16(pv[0],  pv[1]);
            unsigned w1 = cvt_pk_bf16(pv[2],  pv[3]);
            unsigned w2 = cvt_pk_bf16(pv[4],  pv[5]);
            unsigned w3 = cvt_pk_bf16(pv[6],  pv[7]);
            unsigned w4 = cvt_pk_bf16(pv[8],  pv[9]);
            unsigned w5 = cvt_pk_bf16(pv[10], pv[11]);
            unsigned w6 = cvt_pk_bf16(pv[12], pv[13]);
            unsigned w7 = cvt_pk_bf16(pv[14], pv[15]);
            PLSWAP(w0, w2); PLSWAP(w1, w3);   // frag kv 0..15 : words 0..3
            PLSWAP(w4, w6); PLSWAP(w5, w7);   // frag kv 16..31: words 0..3
            bf16x8 pa0 = __builtin_bit_cast(bf16x8, (uint4){w0, w1, w2, w3});
            bf16x8 pa1 = __builtin_bit_cast(bf16x8, (uint4){w4, w5, w6, w7});

            __builtin_amdgcn_s_setprio(1);
            o0 = MFMA32(pa0, v00, o0);
            o0 = MFMA32(pa1, v10, o0);
            o1 = MFMA32(pa0, v01, o1);
            o1 = MFMA32(pa1, v11, o1);
            __builtin_amdgcn_s_setprio(0);

            kpt += 32 * NDH;
            vt0 += 32; vt1 += 32;
        }

        // merge pair-halves of lsum; transport 1/l to o-layout; store
        lsum += __shfl_xor(lsum, 32);
        if (lane < 32) Fw[qq] = 1.f / lsum;
        f32x4 i0 = *(const f32x4*)&Fw[4 * hi];
        f32x4 i1 = *(const f32x4*)&Fw[8 + 4 * hi];
        f32x4 i2 = *(const f32x4*)&Fw[16 + 4 * hi];
        f32x4 i3 = *(const f32x4*)&Fw[24 + 4 * hi];
        __bf16* ob = Oa + ((size_t)b * NS + q0) * ND + h * 64 + qq;
        #pragma unroll
        for (int g = 0; g < 4; g++) {
            f32x4 iv = (g == 0) ? i0 : (g == 1) ? i1 : (g == 2) ? i2 : i3;
            #pragma unroll
            for (int i = 0; i < 4; i++) {
                const int row = 8 * g + 4 * hi + i;
                ob[(size_t)row * ND]      = (__bf16)(o0[4 * g + i] * iv[i]);
                ob[(size_t)row * ND + 32] = (__bf16)(o1[4 * g + i] * iv[i]);
            }
        }
    }
}

extern "C" void kernel_launch(void* const* d_in, const int* in_sizes, int n_in,
                              void* d_out, int out_size, void* d_ws, size_t ws_size,
                              hipStream_t stream) {
    const float* x  = (const float*)d_in[0];
    const float* wq = (const float*)d_in[1];
    const float* wk = (const float*)d_in[2];
    const float* wv = (const float*)d_in[3];
    const float* wo = (const float*)d_in[4];
    char* ws = (char*)d_ws;

    __bf16* xb  = (__bf16*)(ws);                      // 16 MB  [M,K]
    __bf16* wqb = (__bf16*)(ws + (16ull << 20));      //  2 MB
    __bf16* wkb = (__bf16*)(ws + (18ull << 20));
    __bf16* wvb = (__bf16*)(ws + (20ull << 20));
    __bf16* wob = (__bf16*)(ws + (22ull << 20));
    __bf16* Qb  = (__bf16*)(ws + (24ull << 20));      // 16 MB [B,H,S,Dh]
    __bf16* Kb  = (__bf16*)(ws + (40ull << 20));      // 16 MB [B,H,S,Dh]
    __bf16* Vtb = (__bf16*)(ws + (56ull << 20));      // 16 MB [B,H,Dh,S]
    __bf16* Ab  = (__bf16*)(ws + (72ull << 20));      // 16 MB [B,S,D]
    float* out  = (float*)d_out;

    cast4<<<dim3(NM * ND / 1024), 256, 0, stream>>>(x,  xb,  NM * ND);
    cast4<<<dim3(ND * ND / 1024), 256, 0, stream>>>(wq, wqb, ND * ND);
    cast4<<<dim3(ND * ND / 1024), 256, 0, stream>>>(wk, wkb, ND * ND);
    cast4<<<dim3(ND * ND / 1024), 256, 0, stream>>>(wv, wvb, ND * ND);
    cast4<<<dim3(ND * ND / 1024), 256, 0, stream>>>(wo, wob, ND * ND);

    gemm128<0><<<dim3(NM/128, ND/128, 3), 256, 0, stream>>>(
        xb, wqb, wkb, wvb, Qb, Kb, Vtb, nullptr);

    attn32<<<dim3(512), 256, 0, stream>>>(Qb, Kb, Vtb, Ab);

    gemm128<1><<<dim3(NM/128, ND/128), 256, 0, stream>>>(
        Ab, wob, nullptr, nullptr, nullptr, nullptr, nullptr, out);
}